// Round 6
// baseline (22.377 us; speedup 1.0000x reference)
//
#include <hip/hip_runtime.h>

constexpr int NE = 8;       // N_ELEMENT
constexpr int NL = 32;      // N_LINES
constexpr int MB = 512;     // MINIBATCH
constexpr int SN = 1024;    // SAMPLE_N
constexpr float KS   = 0.01f / 1024.0f;  // SAMPLE_CM / SAMPLE_N
constexpr float I0   = 100000.0f;        // PROBE_I0
constexpr float OUTS = 0.05f;            // DET_SOLID_ANGLE_RATIO * SIGNAL_ATT

// Wave-specialized fused kernel. One block (768 threads = 12 waves) per batch
// row b:
//   waves 0-3  (t<256): xp load -> prefix scan -> weighted conc into LDS
//   waves 4-11 (t>=256): stream SA. Their first 2 lines' loads are issued at
//     cycle 0 (before any barrier), so the 64 MB SA stream overlaps the
//     xp+scan phase. They idle at the barriers while loads fly, then dot
//     against s_wx from LDS.
__global__ __launch_bounds__(768, 6)
void ppm_fused(const float* __restrict__ xp,   // [8][512][1024]
               const float* __restrict__ mu,   // [8]
               const float* __restrict__ fl,   // [32]
               const float* __restrict__ SA,   // [32][512*1024]
               float* __restrict__ out)        // [32*512 fl_signal | 512 trans]
{
    const int b    = blockIdx.x;
    const int t    = threadIdx.x;
    const int lane = t & 63;

    __shared__ float s_wave[4];
    __shared__ float s_wx[NE][SN];              // weighted conc, 32 KB

    // dot-group identifiers (valid when t >= 256)
    const int dw = (t >> 6) - 4;                // 0..7; owns lines 4dw..4dw+3
    const size_t sarow = (size_t)b * SN;

    float x[NE][4];                             // scan group only
    float4 sa0[4], sa1[4];                      // dot group pass-A registers
    float e1 = 0.f, e2 = 0.f, e3 = 0.f, T = 0.f, incl = 0.f;

    if (t < 256) {
        // ---- scan group: load xp (float4) and wave-scan chunk totals ----
        const int wv = t >> 6;
        #pragma unroll
        for (int e = 0; e < NE; ++e) {
            const float4 v = reinterpret_cast<const float4*>(
                xp + (size_t)e * (MB * SN) + sarow)[t];
            x[e][0] = v.x; x[e][1] = v.y; x[e][2] = v.z; x[e][3] = v.w;
        }
        float a0 = 0.f, a1 = 0.f, a2 = 0.f, a3 = 0.f;
        #pragma unroll
        for (int e = 0; e < NE; ++e) {
            const float m = mu[e];
            a0 = fmaf(m, x[e][0], a0);
            a1 = fmaf(m, x[e][1], a1);
            a2 = fmaf(m, x[e][2], a2);
            a3 = fmaf(m, x[e][3], a3);
        }
        e1 = a0; e2 = a0 + a1; e3 = e2 + a2; T = e3 + a3;
        incl = T;
        #pragma unroll
        for (int d = 1; d < 64; d <<= 1) {
            const float v = __shfl_up(incl, d, 64);
            if (lane >= d) incl += v;
        }
        if (lane == 63) s_wave[wv] = incl;
    } else {
        // ---- dot group: issue pass-A SA loads immediately (lines 4dw, 4dw+1)
        const float4* sa4a = reinterpret_cast<const float4*>(
            SA + ((size_t)(4 * dw)     << 19) + sarow);   // MB*SN = 2^19
        const float4* sa4b = reinterpret_cast<const float4*>(
            SA + ((size_t)(4 * dw + 1) << 19) + sarow);
        #pragma unroll
        for (int j = 0; j < 4; ++j) sa0[j] = sa4a[lane + 64 * j];
        #pragma unroll
        for (int j = 0; j < 4; ++j) sa1[j] = sa4b[lane + 64 * j];
    }

    __syncthreads();   // barrier 1: s_wave visible

    if (t < 256) {
        const int wv = t >> 6;
        float woff = 0.f;
        #pragma unroll
        for (int w2 = 0; w2 < 4; ++w2) woff += (w2 < wv) ? s_wave[w2] : 0.f;
        const float bex = woff + (incl - T);

        if (t == 0) {
            out[NL * MB + b] = KS * (s_wave[0] + s_wave[1] + s_wave[2] + s_wave[3]);
        }

        const float w0 = I0 * __expf(-KS * bex);
        const float w1 = I0 * __expf(-KS * (bex + e1));
        const float w2 = I0 * __expf(-KS * (bex + e2));
        const float w3 = I0 * __expf(-KS * (bex + e3));

        #pragma unroll
        for (int e = 0; e < NE; ++e) {
            reinterpret_cast<float4*>(&s_wx[e][0])[t] =
                make_float4(w0 * x[e][0], w1 * x[e][1], w2 * x[e][2], w3 * x[e][3]);
        }
    }

    __syncthreads();   // barrier 2: s_wx visible

    if (t >= 256) {
        // wx fragment for element e = dw (shared by this wave's 4 lines)
        float4 wx[4];
        const float4* wx4 = reinterpret_cast<const float4*>(&s_wx[dw][0]);
        #pragma unroll
        for (int j = 0; j < 4; ++j) wx[j] = wx4[lane + 64 * j];

        float acc[4];

        // pass B, line 4dw+2: issue loads, then consume pass-A regs
        const float4* sa4c = reinterpret_cast<const float4*>(
            SA + ((size_t)(4 * dw + 2) << 19) + sarow);
        float4 sa2[4];
        #pragma unroll
        for (int j = 0; j < 4; ++j) sa2[j] = sa4c[lane + 64 * j];

        acc[0] = 0.f; acc[1] = 0.f;
        #pragma unroll
        for (int j = 0; j < 4; ++j) {
            acc[0] += wx[j].x * sa0[j].x + wx[j].y * sa0[j].y
                    + wx[j].z * sa0[j].z + wx[j].w * sa0[j].w;
            acc[1] += wx[j].x * sa1[j].x + wx[j].y * sa1[j].y
                    + wx[j].z * sa1[j].z + wx[j].w * sa1[j].w;
        }

        // pass B, line 4dw+3
        const float4* sa4d = reinterpret_cast<const float4*>(
            SA + ((size_t)(4 * dw + 3) << 19) + sarow);
        float4 sa3[4];
        #pragma unroll
        for (int j = 0; j < 4; ++j) sa3[j] = sa4d[lane + 64 * j];

        acc[2] = 0.f;
        #pragma unroll
        for (int j = 0; j < 4; ++j) {
            acc[2] += wx[j].x * sa2[j].x + wx[j].y * sa2[j].y
                    + wx[j].z * sa2[j].z + wx[j].w * sa2[j].w;
        }
        acc[3] = 0.f;
        #pragma unroll
        for (int j = 0; j < 4; ++j) {
            acc[3] += wx[j].x * sa3[j].x + wx[j].y * sa3[j].y
                    + wx[j].z * sa3[j].z + wx[j].w * sa3[j].w;
        }

        // wave shuffle reductions
        #pragma unroll
        for (int li = 0; li < 4; ++li) {
            #pragma unroll
            for (int d = 32; d >= 1; d >>= 1) acc[li] += __shfl_down(acc[li], d, 64);
        }
        if (lane == 0) {
            #pragma unroll
            for (int li = 0; li < 4; ++li) {
                const int l = 4 * dw + li;
                out[l * MB + b] = OUTS * fl[l] * acc[li];
            }
        }
    }
}

extern "C" void kernel_launch(void* const* d_in, const int* in_sizes, int n_in,
                              void* d_out, int out_size, void* d_ws, size_t ws_size,
                              hipStream_t stream) {
    const float* xp = (const float*)d_in[0];
    const float* mu = (const float*)d_in[1];
    const float* fl = (const float*)d_in[2];
    const float* SA = (const float*)d_in[3];
    float* out = (float*)d_out;
    ppm_fused<<<MB, 768, 0, stream>>>(xp, mu, fl, SA, out);
}

// Round 7
// 19.414 us; speedup vs baseline: 1.1526x; 1.1526x over previous
//
#include <hip/hip_runtime.h>

constexpr int NE = 8;       // N_ELEMENT
constexpr int NL = 32;      // N_LINES
constexpr int MB = 512;     // MINIBATCH
constexpr int SN = 1024;    // SAMPLE_N
constexpr float KS   = 0.01f / 1024.0f;  // SAMPLE_CM / SAMPLE_N
constexpr float I0   = 100000.0f;        // PROBE_I0
constexpr float OUTS = 0.05f;            // DET_SOLID_ANGLE_RATIO * SIGNAL_ATT

// R1 structure (best known: 18.4 us) + deeper memory-level parallelism:
//   - xp loads issued first (oldest in vmcnt queue -> scan waits only them)
//   - SA lines 0..15 issued BEFORE the scan (in flight across it)
//   - SA lines 16..31 issued right after barrier 1, before half-A consumption
// One block per batch row b; 256 threads; thread t owns samples 4t..4t+3.
__global__ __launch_bounds__(256)
void ppm_kernel(const float* __restrict__ xp,   // [8][512][1024]
                const float* __restrict__ mu,   // [8]
                const float* __restrict__ fl,   // [32]
                const float* __restrict__ SA,   // [32][512*1024]
                float* __restrict__ out)        // [32*512 fl_signal | 512 trans]
{
    const int b    = blockIdx.x;
    const int t    = threadIdx.x;
    const int lane = t & 63;
    const int wv   = t >> 6;

    __shared__ float s_wave[4];
    __shared__ float s_acc[256 * 33];   // [thread][line], stride 33: conflict-free
    __shared__ float s_part[256];       // [group(8)][line(32)]

    const size_t sarow = (size_t)b * SN;

    // ---- 1) xp loads FIRST: 8 elements x 4 samples (float4, coalesced) ----
    float x[NE][4];
    #pragma unroll
    for (int e = 0; e < NE; ++e) {
        const float4 v = reinterpret_cast<const float4*>(
            xp + (size_t)e * (MB * SN) + sarow)[t];
        x[e][0] = v.x; x[e][1] = v.y; x[e][2] = v.z; x[e][3] = v.w;
    }

    // ---- 2) SA half A (lines 0..15) issued before the scan ----
    float4 sa[16];
    #pragma unroll
    for (int l = 0; l < 16; ++l) {
        sa[l] = reinterpret_cast<const float4*>(
            SA + ((size_t)l << 19) + sarow)[t];          // MB*SN = 2^19
    }

    // ---- 3) attenuation increments + prefix scan (waits xp only) ----
    float a0 = 0.f, a1 = 0.f, a2 = 0.f, a3 = 0.f;
    #pragma unroll
    for (int e = 0; e < NE; ++e) {
        const float m = mu[e];
        a0 = fmaf(m, x[e][0], a0);
        a1 = fmaf(m, x[e][1], a1);
        a2 = fmaf(m, x[e][2], a2);
        a3 = fmaf(m, x[e][3], a3);
    }
    const float e1 = a0, e2 = a0 + a1, e3 = e2 + a2;
    const float T  = e3 + a3;

    float incl = T;
    #pragma unroll
    for (int d = 1; d < 64; d <<= 1) {
        const float v = __shfl_up(incl, d, 64);
        if (lane >= d) incl += v;
    }
    if (lane == 63) s_wave[wv] = incl;
    __syncthreads();

    float woff = 0.f;
    #pragma unroll
    for (int w2 = 0; w2 < 4; ++w2) woff += (w2 < wv) ? s_wave[w2] : 0.f;
    const float bex = woff + (incl - T);

    if (t == 0) {
        out[NL * MB + b] = KS * (s_wave[0] + s_wave[1] + s_wave[2] + s_wave[3]);
    }

    const float w0  = I0 * __expf(-KS * bex);
    const float w1  = I0 * __expf(-KS * (bex + e1));
    const float w2f = I0 * __expf(-KS * (bex + e2));
    const float w3  = I0 * __expf(-KS * (bex + e3));
    #pragma unroll
    for (int e = 0; e < NE; ++e) {
        x[e][0] *= w0; x[e][1] *= w1; x[e][2] *= w2f; x[e][3] *= w3;
    }

    // ---- 4) issue SA half B (lines 16..31), then consume half A ----
    float4 sb[16];
    #pragma unroll
    for (int l = 0; l < 16; ++l) {
        sb[l] = reinterpret_cast<const float4*>(
            SA + ((size_t)(l + 16) << 19) + sarow)[t];
    }
    #pragma unroll
    for (int l = 0; l < 16; ++l) {
        const int e = l >> 2;
        s_acc[t * 33 + l] = x[e][0] * sa[l].x + x[e][1] * sa[l].y
                          + x[e][2] * sa[l].z + x[e][3] * sa[l].w;
    }
    #pragma unroll
    for (int l = 0; l < 16; ++l) {
        const int e = 4 + (l >> 2);
        s_acc[t * 33 + 16 + l] = x[e][0] * sb[l].x + x[e][1] * sb[l].y
                               + x[e][2] * sb[l].z + x[e][3] * sb[l].w;
    }
    __syncthreads();

    // ---- 5) block reduction: 256 partials per line -> 8 group partials ----
    {
        const int l = t & 31, g = t >> 5;
        float s = 0.f;
        #pragma unroll
        for (int j = 0; j < 32; ++j) s += s_acc[(g * 32 + j) * 33 + l];
        s_part[t] = s;   // t == g*32 + l
    }
    __syncthreads();

    // ---- 6) final: 8 group partials -> fl_signal[l][b] ----
    if (t < 32) {
        float tot = 0.f;
        #pragma unroll
        for (int g2 = 0; g2 < 8; ++g2) tot += s_part[g2 * 32 + t];
        out[t * MB + b] = OUTS * fl[t] * tot;
    }
}

extern "C" void kernel_launch(void* const* d_in, const int* in_sizes, int n_in,
                              void* d_out, int out_size, void* d_ws, size_t ws_size,
                              hipStream_t stream) {
    const float* xp = (const float*)d_in[0];
    const float* mu = (const float*)d_in[1];
    const float* fl = (const float*)d_in[2];
    const float* SA = (const float*)d_in[3];
    float* out = (float*)d_out;
    ppm_kernel<<<MB, 256, 0, stream>>>(xp, mu, fl, SA, out);
}